// Round 16
// baseline (402.022 us; speedup 1.0000x reference)
//
#include <hip/hip_runtime.h>

#define NN 100000
#define NE 1600000
#define H  128
#define NG 512
#define NC 10
#define NBUCK  391      // ceil(NN/256) dst buckets (dst>>8), 256 nodes each
#define CHUNK  4096     // edges per pass-A block
#define BINCAP 4608     // per-bucket capacity in binned (mean 4092 + 8 sigma)
#define EDCAP  6144     // per-bucket capacity in edata (256 nodes, avg L~21 + slack)

typedef _Float16 f16;
typedef __attribute__((ext_vector_type(8))) _Float16 f16x8;
typedef __attribute__((ext_vector_type(4))) _Float16 f16x4;
typedef __attribute__((ext_vector_type(4))) float    f32x4;

// ---------------------------------------------------------------- utilities
__device__ __forceinline__ int lower_bound_i(const int* __restrict__ a, int n, int val) {
    int lo = 0, hi = n;
    while (lo < hi) {
        int mid = (lo + hi) >> 1;
        if (a[mid] < val) lo = mid + 1; else hi = mid;
    }
    return lo;
}

// ---------------------------------------------------------------- pass A: bin edges by coarse bucket
// bucket b segment = binned[b*BINCAP ...]; payload int: src (17b) | dstloc (8b) << 17
__global__ __launch_bounds__(512) void binA_kernel(const int* __restrict__ src,
                                                   const int* __restrict__ dst,
                                                   int* __restrict__ bcur,
                                                   int* __restrict__ binned) {
    __shared__ int hist[NBUCK];
    __shared__ int lbase[NBUCK];
    __shared__ int gbase[NBUCK];
    __shared__ int cur[NBUCK];
    __shared__ int stage[CHUNK];
    __shared__ int destp[CHUNK];
    __shared__ int ws2[8];
    int t  = threadIdx.x;
    int lane = t & 63, wid = t >> 6;
    int e0 = blockIdx.x * CHUNK;
    int cnt = NE - e0; if (cnt > CHUNK) cnt = CHUNK;

    if (t < NBUCK) hist[t] = 0;
    __syncthreads();

    int s_[8], d_[8];
    #pragma unroll
    for (int i = 0; i < 8; ++i) {
        int e = e0 + i * 512 + t;
        if (e < NE) {
            s_[i] = src[e]; d_[i] = dst[e];
            atomicAdd(&hist[d_[i] >> 8], 1);
        } else { s_[i] = -1; d_[i] = 0; }
    }
    __syncthreads();

    // parallel exclusive scan of hist over NBUCK entries (512 threads, wave-scan)
    int v = (t < NBUCK) ? hist[t] : 0;
    int incl = v;
    #pragma unroll
    for (int d = 1; d < 64; d <<= 1) { int u = __shfl_up(incl, d, 64); if (lane >= d) incl += u; }
    if (lane == 63) ws2[wid] = incl;
    __syncthreads();
    int wb = 0;
    for (int w = 0; w < wid; ++w) wb += ws2[w];
    if (t < NBUCK) {
        int lb = wb + incl - v;
        lbase[t] = lb;
        cur[t]   = lb;
        gbase[t] = t * BINCAP + atomicAdd(&bcur[t], hist[t]);
    }
    __syncthreads();

    #pragma unroll
    for (int i = 0; i < 8; ++i) {
        if (s_[i] >= 0) {
            int s = s_[i], d = d_[i];
            int b = d >> 8;
            int r = atomicAdd(&cur[b], 1);
            stage[r] = s | ((d & 255) << 17);
            destp[r] = gbase[b] + (r - lbase[b]);
        }
    }
    __syncthreads();

    #pragma unroll
    for (int i = 0; i < 8; ++i) {
        int idx = i * 512 + t;
        if (idx < cnt) binned[destp[idx]] = stage[idx];
    }
}

// ---------------------------------------------------------------- pass B: fine hist + scan + dis + padded CSR placement
// 256 threads, one node per thread (256-node buckets). Node list: [self]+edges+pad(NN)
// rounded to multiple of 8. offs_pk[d] = global_base | (L/8)<<22. Block 0 zeroes pad row.
__global__ __launch_bounds__(256) void binB_kernel(const int* __restrict__ binned,
                                                   const int* __restrict__ bcnt,
                                                   int* __restrict__ edata,
                                                   int* __restrict__ offs_pk,
                                                   float* __restrict__ dis,
                                                   f16* __restrict__ hwb) {
    __shared__ int cnt[256];
    __shared__ int cursor[256];
    __shared__ int ws[4];
    int b = blockIdx.x, t = threadIdx.x;
    int lane = t & 63, wid = t >> 6;
    if (b == 0 && t < 64) ((int*)(hwb + (size_t)NN * H))[t] = 0;   // zero pad row
    cnt[t] = 0;
    __syncthreads();
    int lo = b * BINCAP, hi = lo + bcnt[b];
    for (int e = lo + t; e < hi; e += 256) {
        atomicAdd(&cnt[(binned[e] >> 17) & 255], 1);
    }
    __syncthreads();
    int gd = (b << 8) + t;
    int c = cnt[t];
    int L = (gd < NN) ? ((c + 8) & ~7) : 0;   // self + edges, rounded up to 8
    // block-wide exclusive scan of L
    int incl = L;
    #pragma unroll
    for (int d = 1; d < 64; d <<= 1) { int u = __shfl_up(incl, d, 64); if (lane >= d) incl += u; }
    if (lane == 63) ws[wid] = incl;
    __syncthreads();
    int wbase = 0;
    for (int w = 0; w < wid; ++w) wbase += ws[w];
    int lbase = wbase + incl - L;
    int epoff = b * EDCAP;
    int gbase = epoff + lbase;
    if (gd < NN) {
        offs_pk[gd] = gbase | ((L >> 3) << 22);
        dis[gd] = rsqrtf((float)c + 1.0f);
        edata[gbase] = gd;                                       // self entry
        for (int i = c + 1; i < L; ++i) edata[gbase + i] = NN;   // pads -> zero row
    }
    cursor[t] = lbase + 1;
    __syncthreads();
    for (int e = lo + t; e < hi; e += 256) {
        int p = binned[e];
        int dloc = (p >> 17) & 255;
        int r = atomicAdd(&cursor[dloc], 1);
        edata[epoff + r] = p & 0x1FFFF;
    }
}

// ---------------------------------------------------------------- MFMA GEMM: hw' = fp16(dis * ((in0 [+ in1]) @ W))
// 512 threads = 8 waves; wave owns 32 rows; 256 rows/block. SPLIT-PHASE staging:
// stage W_hi -> sync -> issue W_lo staging (disjoint sW[1]) -> MFMA-hi burst (hides the
// lo re-read latency) -> sync -> MFMA-lo. A frags loaded first (fly under hi staging).
// Swapped-operand MFMA -> D lane = node row, regs = 4 W-cols -> direct 8B stores.
template <int FP32IN>
__global__ __launch_bounds__(512) void gemm_kernel(const void* __restrict__ in0,
                                                   const f16* __restrict__ in1,
                                                   const float* __restrict__ W,
                                                   const float* __restrict__ dis,
                                                   f16* __restrict__ hw) {
    __shared__ f16x8 sW[2][128 * 16];   // [c*128 + n]: chunk = W^T[n][c*8..c*8+7]
    int t = threadIdx.x;
    int l = t & 63, w = t >> 6;
    int lr = l & 15, lq = l >> 4;
    int rowb = blockIdx.x * 256 + w * 32;

    // A fragments first — independent loads issue ahead of the W staging chain
    f16x8 aF[2][4];
    #pragma unroll
    for (int rt = 0; rt < 2; ++rt) {
        int grow = rowb + rt * 16 + lr;
        if (grow >= NN) grow = NN - 1;
        #pragma unroll
        for (int ks = 0; ks < 4; ++ks) {
            int c = ks * 4 + lq;                 // k-chunk (16B) index 0..15
            f16x8 v;
            if (FP32IN) {
                const float* xp = (const float*)in0 + (size_t)grow * H + c * 8;
                f32x4 u0 = *(const f32x4*)xp;
                f32x4 u1 = *(const f32x4*)(xp + 4);
                #pragma unroll
                for (int u = 0; u < 4; ++u) { v[u] = (f16)u0[u]; v[u + 4] = (f16)u1[u]; }
            } else {
                v = *((const f16x8*)in0 + (size_t)grow * 16 + c);
                if (in1) {
                    f16x8 uu = *((const f16x8*)in1 + (size_t)grow * 16 + c);
                    v = v + uu;
                }
            }
            aF[rt][ks] = v;
        }
    }

    // stage W_hi: thread -> chunk (n = ch&127, c = ch>>7); reads coalesced over n
    #pragma unroll
    for (int i = 0; i < 4; ++i) {
        int ch = i * 512 + t;           // 0..2047
        int n = ch & 127, c = ch >> 7;
        f16x8 hi;
        #pragma unroll
        for (int j = 0; j < 8; ++j) hi[j] = (f16)W[(c * 8 + j) * H + n];
        sW[0][c * 128 + n] = hi;
    }
    __syncthreads();

    // stage W_lo (writes sW[1], disjoint from sW[0] reads) — loads hoist above MFMA-hi
    #pragma unroll
    for (int i = 0; i < 4; ++i) {
        int ch = i * 512 + t;
        int n = ch & 127, c = ch >> 7;
        f16x8 lo;
        #pragma unroll
        for (int j = 0; j < 8; ++j) {
            float v = W[(c * 8 + j) * H + n];
            f16 hv = (f16)v;
            lo[j] = (f16)(v - (float)hv);
        }
        sW[1][c * 128 + n] = lo;
    }

    f32x4 acc[2][8];
    #pragma unroll
    for (int rt = 0; rt < 2; ++rt)
        #pragma unroll
        for (int ct = 0; ct < 8; ++ct)
            acc[rt][ct] = (f32x4){0.f, 0.f, 0.f, 0.f};

    // MFMA-hi burst (64 MFMAs/wave) — lo staging latency hides under this
    #pragma unroll
    for (int ks = 0; ks < 4; ++ks) {
        int c = ks * 4 + lq;
        #pragma unroll
        for (int ct = 0; ct < 8; ++ct) {
            int n = ct * 16 + lr;
            f16x8 bF = sW[0][c * 128 + n];
            acc[0][ct] = __builtin_amdgcn_mfma_f32_16x16x32_f16(bF, aF[0][ks], acc[0][ct], 0, 0, 0);
            acc[1][ct] = __builtin_amdgcn_mfma_f32_16x16x32_f16(bF, aF[1][ks], acc[1][ct], 0, 0, 0);
        }
    }
    __syncthreads();
    // MFMA-lo burst
    #pragma unroll
    for (int ks = 0; ks < 4; ++ks) {
        int c = ks * 4 + lq;
        #pragma unroll
        for (int ct = 0; ct < 8; ++ct) {
            int n = ct * 16 + lr;
            f16x8 bF = sW[1][c * 128 + n];
            acc[0][ct] = __builtin_amdgcn_mfma_f32_16x16x32_f16(bF, aF[0][ks], acc[0][ct], 0, 0, 0);
            acc[1][ct] = __builtin_amdgcn_mfma_f32_16x16x32_f16(bF, aF[1][ks], acc[1][ct], 0, 0, 0);
        }
    }

    // store hw' = dis * result: node = lane&15 of each tile; 4 regs = W-cols ct*16+lq*4..+3
    #pragma unroll
    for (int rt = 0; rt < 2; ++rt) {
        int grow = rowb + rt * 16 + lr;
        if (grow < NN) {
            float dv = dis[grow];
            #pragma unroll
            for (int ct = 0; ct < 8; ++ct) {
                f16x4 o;
                #pragma unroll
                for (int r = 0; r < 4; ++r) o[r] = (f16)(dv * acc[rt][ct][r]);
                *(f16x4*)&hw[(size_t)grow * H + ct * 16 + lq * 4] = o;
            }
        }
    }
}

// ---------------------------------------------------------------- aggregation (fp16 out)
// out[d] = relu(dis[d] * sum_slots hw'[slot] + bias); slots = [self]+edges+pads, pad-to-8
// nit8 is wave-uniform: special-case 1/2/3 with ALL gathers issued flat (2/4/6 in flight),
// vectorized int2/int4 edata loads; generic loop only for nit8>=4 (12% of waves).
__global__ __launch_bounds__(256) void agg_kernel(const f16* __restrict__ hw,
                                                  const float* __restrict__ dis,
                                                  const int* __restrict__ offs_pk,
                                                  const int* __restrict__ edata,
                                                  const float* __restrict__ bias,
                                                  f16* __restrict__ outh) {
    int wid  = threadIdx.x >> 6;
    int lane = threadIdx.x & 63;
    int node = blockIdx.x * 4 + wid;
    if (node >= NN) return;
    int q  = lane >> 4;
    int j8 = (lane & 15) * 8;
    int w = offs_pk[node];
    int beg = w & 0x3FFFFF;
    int nit8 = (unsigned)w >> 22;
    float acc[8];
    #pragma unroll
    for (int u = 0; u < 8; ++u) acc[u] = 0.f;

    if (nit8 == 2) {
        int4 s = *(const int4*)&edata[beg + q * 4];
        f16x8 v0 = *(const f16x8*)&hw[(size_t)s.x * H + j8];
        f16x8 v1 = *(const f16x8*)&hw[(size_t)s.y * H + j8];
        f16x8 v2 = *(const f16x8*)&hw[(size_t)s.z * H + j8];
        f16x8 v3 = *(const f16x8*)&hw[(size_t)s.w * H + j8];
        f16x8 vt = (v0 + v1) + (v2 + v3);
        #pragma unroll
        for (int u = 0; u < 8; ++u) acc[u] += (float)vt[u];
    } else if (nit8 == 3) {
        int4 s  = *(const int4*)&edata[beg + q * 4];
        int2 s2 = *(const int2*)&edata[beg + 16 + q * 2];
        f16x8 v0 = *(const f16x8*)&hw[(size_t)s.x * H + j8];
        f16x8 v1 = *(const f16x8*)&hw[(size_t)s.y * H + j8];
        f16x8 v2 = *(const f16x8*)&hw[(size_t)s.z * H + j8];
        f16x8 v3 = *(const f16x8*)&hw[(size_t)s.w * H + j8];
        f16x8 v4 = *(const f16x8*)&hw[(size_t)s2.x * H + j8];
        f16x8 v5 = *(const f16x8*)&hw[(size_t)s2.y * H + j8];
        f16x8 vt = ((v0 + v1) + (v2 + v3)) + (v4 + v5);
        #pragma unroll
        for (int u = 0; u < 8; ++u) acc[u] += (float)vt[u];
    } else if (nit8 == 1) {
        int2 s2 = *(const int2*)&edata[beg + q * 2];
        f16x8 v0 = *(const f16x8*)&hw[(size_t)s2.x * H + j8];
        f16x8 v1 = *(const f16x8*)&hw[(size_t)s2.y * H + j8];
        f16x8 vt = v0 + v1;
        #pragma unroll
        for (int u = 0; u < 8; ++u) acc[u] += (float)vt[u];
    } else {
        int it = 0;
        for (; it + 2 <= nit8; it += 2) {
            int4 s = *(const int4*)&edata[beg + it * 8 + q * 4];
            f16x8 v0 = *(const f16x8*)&hw[(size_t)s.x * H + j8];
            f16x8 v1 = *(const f16x8*)&hw[(size_t)s.y * H + j8];
            f16x8 v2 = *(const f16x8*)&hw[(size_t)s.z * H + j8];
            f16x8 v3 = *(const f16x8*)&hw[(size_t)s.w * H + j8];
            f16x8 vt = (v0 + v1) + (v2 + v3);
            #pragma unroll
            for (int u = 0; u < 8; ++u) acc[u] += (float)vt[u];
        }
        if (nit8 & 1) {
            int2 s2 = *(const int2*)&edata[beg + (nit8 - 1) * 8 + q * 2];
            f16x8 v0 = *(const f16x8*)&hw[(size_t)s2.x * H + j8];
            f16x8 v1 = *(const f16x8*)&hw[(size_t)s2.y * H + j8];
            f16x8 vt = v0 + v1;
            #pragma unroll
            for (int u = 0; u < 8; ++u) acc[u] += (float)vt[u];
        }
    }
    #pragma unroll
    for (int u = 0; u < 8; ++u) {
        acc[u] += __shfl_xor(acc[u], 16, 64);
        acc[u] += __shfl_xor(acc[u], 32, 64);
    }
    if (q == 0) {
        float dv = dis[node];
        f16x8 o;
        #pragma unroll
        for (int u = 0; u < 8; ++u) o[u] = (f16)fmaxf(dv * acc[u] + bias[j8 + u], 0.f);
        *(f16x8*)&outh[(size_t)node * H + j8] = o;
    }
}

// ---------------------------------------------------------------- mean-pool + linear head (4-way node-parallel)
__global__ __launch_bounds__(512) void pool_kernel(const f16* __restrict__ h,
                                                   const int* __restrict__ batch,
                                                   const float* __restrict__ linW,
                                                   const float* __restrict__ linb,
                                                   float* __restrict__ out) {
    __shared__ float pld[4][H];
    int g = blockIdx.x;
    int t = threadIdx.x;
    int f = t & 127, quad = t >> 7;
    int lo = lower_bound_i(batch, NN, g);
    int hi = lower_bound_i(batch, NN, g + 1);
    float sum = 0.f;
    for (int n = lo + quad; n < hi; n += 4) sum += (float)h[(size_t)n * H + f];
    pld[quad][f] = sum;
    __syncthreads();
    if (t < H) {
        float cnt = (float)(hi - lo);
        pld[0][t] = (pld[0][t] + pld[1][t] + pld[2][t] + pld[3][t]) / fmaxf(cnt, 1.0f);
    }
    __syncthreads();
    if (t < NC) {
        float acc = linb[t];
        #pragma unroll 4
        for (int j = 0; j < H; ++j) acc += pld[0][j] * linW[j * NC + t];
        out[g * NC + t] = acc;
    }
}

// ---------------------------------------------------------------- launch
extern "C" void kernel_launch(void* const* d_in, const int* in_sizes, int n_in,
                              void* d_out, int out_size, void* d_ws, size_t ws_size,
                              hipStream_t stream) {
    const float* x     = (const float*)d_in[0];
    const int*   ei    = (const int*)d_in[1];
    const int*   batch = (const int*)d_in[2];
    const float* W0    = (const float*)d_in[3];
    const float* b0    = (const float*)d_in[4];
    const float* Ws    = (const float*)d_in[5];
    const float* bs    = (const float*)d_in[6];
    const float* linW  = (const float*)d_in[7];
    const float* linb  = (const float*)d_in[8];
    const int* src = ei;
    const int* dst = ei + NE;

    char* p = (char*)d_ws;
    auto alloc = [&](size_t bytes) -> void* {
        void* r = (void*)p;
        p += (bytes + 255) & ~(size_t)255;
        return r;
    };
    f16*   buf0    = (f16*)alloc((size_t)NN * H * 2);
    f16*   buf1    = (f16*)alloc((size_t)NN * H * 2);
    f16*   buf2    = (f16*)alloc((size_t)NN * H * 2);
    f16*   hwb     = (f16*)alloc((size_t)(NN + 1) * H * 2);   // row NN = zero row for pads
    float* dis     = (float*)alloc((size_t)NN * 4);
    int*   offs_pk = (int*)alloc((size_t)NN * 4);
    int*   binned  = (int*)alloc((size_t)NBUCK * BINCAP * 4);
    int*   edata   = (int*)alloc((size_t)NBUCK * EDCAP * 4);
    int*   bcur    = (int*)alloc((size_t)NBUCK * 4);

    hipMemsetAsync(bcur, 0, (size_t)NBUCK * 4, stream);

    binA_kernel<<<(NE + CHUNK - 1) / CHUNK, 512, 0, stream>>>(src, dst, bcur, binned);
    binB_kernel<<<NBUCK, 256, 0, stream>>>(binned, bcur, edata, offs_pk, dis, hwb);

    int gemm_grid = (NN + 255) / 256;
    int agg_grid  = (NN + 3) / 4;
    size_t HH = (size_t)H * H;

    gemm_kernel<1><<<gemm_grid, 512, 0, stream>>>(x, nullptr, W0, dis, hwb);
    agg_kernel<<<agg_grid, 256, 0, stream>>>(hwb, dis, offs_pk, edata, b0, buf0);
    gemm_kernel<0><<<gemm_grid, 512, 0, stream>>>(buf0, nullptr, Ws, dis, hwb);
    agg_kernel<<<agg_grid, 256, 0, stream>>>(hwb, dis, offs_pk, edata, bs, buf1);
    gemm_kernel<0><<<gemm_grid, 512, 0, stream>>>(buf1, buf0, Ws + HH, dis, hwb);
    agg_kernel<<<agg_grid, 256, 0, stream>>>(hwb, dis, offs_pk, edata, bs + H, buf2);
    gemm_kernel<0><<<gemm_grid, 512, 0, stream>>>(buf2, buf1, Ws + 2 * HH, dis, hwb);
    agg_kernel<<<agg_grid, 256, 0, stream>>>(hwb, dis, offs_pk, edata, bs + 2 * H, buf0);

    pool_kernel<<<NG, 512, 0, stream>>>(buf0, batch, linW, linb, (float*)d_out);
}

// Round 17
// 391.085 us; speedup vs baseline: 1.0280x; 1.0280x over previous
//
#include <hip/hip_runtime.h>

#define NN 100000
#define NE 1600000
#define H  128
#define NG 512
#define NC 10
#define NBUCK  391      // ceil(NN/256) dst buckets (dst>>8), 256 nodes each
#define CHUNK  4096     // edges per pass-A block
#define BINCAP 4608     // per-bucket capacity in binned (mean 4092 + 8 sigma)
#define EDCAP  6144     // per-bucket capacity in edata (256 nodes, avg L~21 + slack)

typedef _Float16 f16;
typedef __attribute__((ext_vector_type(8))) _Float16 f16x8;
typedef __attribute__((ext_vector_type(4))) _Float16 f16x4;
typedef __attribute__((ext_vector_type(4))) float    f32x4;

// ---------------------------------------------------------------- utilities
__device__ __forceinline__ int lower_bound_i(const int* __restrict__ a, int n, int val) {
    int lo = 0, hi = n;
    while (lo < hi) {
        int mid = (lo + hi) >> 1;
        if (a[mid] < val) lo = mid + 1; else hi = mid;
    }
    return lo;
}

// ---------------------------------------------------------------- pass A: bin edges by coarse bucket
// bucket b segment = binned[b*BINCAP ...]; payload int: src (17b) | dstloc (8b) << 17
__global__ __launch_bounds__(512) void binA_kernel(const int* __restrict__ src,
                                                   const int* __restrict__ dst,
                                                   int* __restrict__ bcur,
                                                   int* __restrict__ binned) {
    __shared__ int hist[NBUCK];
    __shared__ int lbase[NBUCK];
    __shared__ int gbase[NBUCK];
    __shared__ int cur[NBUCK];
    __shared__ int stage[CHUNK];
    __shared__ int destp[CHUNK];
    __shared__ int ws2[8];
    int t  = threadIdx.x;
    int lane = t & 63, wid = t >> 6;
    int e0 = blockIdx.x * CHUNK;
    int cnt = NE - e0; if (cnt > CHUNK) cnt = CHUNK;

    if (t < NBUCK) hist[t] = 0;
    __syncthreads();

    int s_[8], d_[8];
    #pragma unroll
    for (int i = 0; i < 8; ++i) {
        int e = e0 + i * 512 + t;
        if (e < NE) {
            s_[i] = src[e]; d_[i] = dst[e];
            atomicAdd(&hist[d_[i] >> 8], 1);
        } else { s_[i] = -1; d_[i] = 0; }
    }
    __syncthreads();

    // parallel exclusive scan of hist over NBUCK entries (512 threads, wave-scan)
    int v = (t < NBUCK) ? hist[t] : 0;
    int incl = v;
    #pragma unroll
    for (int d = 1; d < 64; d <<= 1) { int u = __shfl_up(incl, d, 64); if (lane >= d) incl += u; }
    if (lane == 63) ws2[wid] = incl;
    __syncthreads();
    int wb = 0;
    for (int w = 0; w < wid; ++w) wb += ws2[w];
    if (t < NBUCK) {
        int lb = wb + incl - v;
        lbase[t] = lb;
        cur[t]   = lb;
        gbase[t] = t * BINCAP + atomicAdd(&bcur[t], hist[t]);
    }
    __syncthreads();

    #pragma unroll
    for (int i = 0; i < 8; ++i) {
        if (s_[i] >= 0) {
            int s = s_[i], d = d_[i];
            int b = d >> 8;
            int r = atomicAdd(&cur[b], 1);
            stage[r] = s | ((d & 255) << 17);
            destp[r] = gbase[b] + (r - lbase[b]);
        }
    }
    __syncthreads();

    #pragma unroll
    for (int i = 0; i < 8; ++i) {
        int idx = i * 512 + t;
        if (idx < cnt) binned[destp[idx]] = stage[idx];
    }
}

// ---------------------------------------------------------------- pass B: fine hist + scan + dis + padded CSR placement
// 256 threads, one node per thread (256-node buckets). Node list: [self]+edges+pad(NN)
// rounded to multiple of 8. offs_pk[d] = global_base | (L/8)<<22. Block 0 zeroes pad row.
__global__ __launch_bounds__(256) void binB_kernel(const int* __restrict__ binned,
                                                   const int* __restrict__ bcnt,
                                                   int* __restrict__ edata,
                                                   int* __restrict__ offs_pk,
                                                   float* __restrict__ dis,
                                                   f16* __restrict__ hwb) {
    __shared__ int cnt[256];
    __shared__ int cursor[256];
    __shared__ int ws[4];
    int b = blockIdx.x, t = threadIdx.x;
    int lane = t & 63, wid = t >> 6;
    if (b == 0 && t < 64) ((int*)(hwb + (size_t)NN * H))[t] = 0;   // zero pad row
    cnt[t] = 0;
    __syncthreads();
    int lo = b * BINCAP, hi = lo + bcnt[b];
    for (int e = lo + t; e < hi; e += 256) {
        atomicAdd(&cnt[(binned[e] >> 17) & 255], 1);
    }
    __syncthreads();
    int gd = (b << 8) + t;
    int c = cnt[t];
    int L = (gd < NN) ? ((c + 8) & ~7) : 0;   // self + edges, rounded up to 8
    // block-wide exclusive scan of L
    int incl = L;
    #pragma unroll
    for (int d = 1; d < 64; d <<= 1) { int u = __shfl_up(incl, d, 64); if (lane >= d) incl += u; }
    if (lane == 63) ws[wid] = incl;
    __syncthreads();
    int wbase = 0;
    for (int w = 0; w < wid; ++w) wbase += ws[w];
    int lbase = wbase + incl - L;
    int epoff = b * EDCAP;
    int gbase = epoff + lbase;
    if (gd < NN) {
        offs_pk[gd] = gbase | ((L >> 3) << 22);
        dis[gd] = rsqrtf((float)c + 1.0f);
        edata[gbase] = gd;                                       // self entry
        for (int i = c + 1; i < L; ++i) edata[gbase + i] = NN;   // pads -> zero row
    }
    cursor[t] = lbase + 1;
    __syncthreads();
    for (int e = lo + t; e < hi; e += 256) {
        int p = binned[e];
        int dloc = (p >> 17) & 255;
        int r = atomicAdd(&cursor[dloc], 1);
        edata[epoff + r] = p & 0x1FFFF;
    }
}

// ---------------------------------------------------------------- MFMA GEMM: hw' = fp16(dis * ((in0 [+ in1]) @ W))
// 512 threads = 8 waves; wave owns 32 rows; 256 rows/block. A frags loaded FIRST (fly under
// W staging). W read fp32 from global, split hi/lo fp16 in-kernel into LDS [c][n] layout.
// Swapped-operand MFMA -> D lane = node row, regs = 4 W-cols -> direct 8B stores.
template <int FP32IN>
__global__ __launch_bounds__(512) void gemm_kernel(const void* __restrict__ in0,
                                                   const f16* __restrict__ in1,
                                                   const float* __restrict__ W,
                                                   const float* __restrict__ dis,
                                                   f16* __restrict__ hw) {
    __shared__ f16x8 sW[2][128 * 16];   // [c*128 + n]: chunk = W^T[n][c*8..c*8+7]
    int t = threadIdx.x;
    int l = t & 63, w = t >> 6;
    int lr = l & 15, lq = l >> 4;
    int rowb = blockIdx.x * 256 + w * 32;

    // A fragments first — independent loads issue ahead of the W staging chain
    f16x8 aF[2][4];
    #pragma unroll
    for (int rt = 0; rt < 2; ++rt) {
        int grow = rowb + rt * 16 + lr;
        if (grow >= NN) grow = NN - 1;
        #pragma unroll
        for (int ks = 0; ks < 4; ++ks) {
            int c = ks * 4 + lq;                 // k-chunk (16B) index 0..15
            f16x8 v;
            if (FP32IN) {
                const float* xp = (const float*)in0 + (size_t)grow * H + c * 8;
                f32x4 u0 = *(const f32x4*)xp;
                f32x4 u1 = *(const f32x4*)(xp + 4);
                #pragma unroll
                for (int u = 0; u < 4; ++u) { v[u] = (f16)u0[u]; v[u + 4] = (f16)u1[u]; }
            } else {
                v = *((const f16x8*)in0 + (size_t)grow * 16 + c);
                if (in1) {
                    f16x8 uu = *((const f16x8*)in1 + (size_t)grow * 16 + c);
                    v = v + uu;
                }
            }
            aF[rt][ks] = v;
        }
    }

    // stage + split W: thread -> chunk (n = ch&127, c = ch>>7); reads coalesced over n
    #pragma unroll
    for (int i = 0; i < 4; ++i) {
        int ch = i * 512 + t;           // 0..2047
        int n = ch & 127, c = ch >> 7;
        f16x8 hi, lo;
        #pragma unroll
        for (int j = 0; j < 8; ++j) {
            float v = W[(c * 8 + j) * H + n];
            f16 hv = (f16)v;
            hi[j] = hv;
            lo[j] = (f16)(v - (float)hv);
        }
        sW[0][c * 128 + n] = hi;
        sW[1][c * 128 + n] = lo;
    }
    __syncthreads();

    f32x4 acc[2][8];
    #pragma unroll
    for (int rt = 0; rt < 2; ++rt)
        #pragma unroll
        for (int ct = 0; ct < 8; ++ct)
            acc[rt][ct] = (f32x4){0.f, 0.f, 0.f, 0.f};

    #pragma unroll
    for (int p = 0; p < 2; ++p) {
        #pragma unroll
        for (int ks = 0; ks < 4; ++ks) {
            int c = ks * 4 + lq;
            #pragma unroll
            for (int ct = 0; ct < 8; ++ct) {
                int n = ct * 16 + lr;
                f16x8 bF = sW[p][c * 128 + n];
                acc[0][ct] = __builtin_amdgcn_mfma_f32_16x16x32_f16(bF, aF[0][ks], acc[0][ct], 0, 0, 0);
                acc[1][ct] = __builtin_amdgcn_mfma_f32_16x16x32_f16(bF, aF[1][ks], acc[1][ct], 0, 0, 0);
            }
        }
    }

    // store hw' = dis * result: node = lane&15 of each tile; 4 regs = W-cols ct*16+lq*4..+3
    #pragma unroll
    for (int rt = 0; rt < 2; ++rt) {
        int grow = rowb + rt * 16 + lr;
        if (grow < NN) {
            float dv = dis[grow];
            #pragma unroll
            for (int ct = 0; ct < 8; ++ct) {
                f16x4 o;
                #pragma unroll
                for (int r = 0; r < 4; ++r) o[r] = (f16)(dv * acc[rt][ct][r]);
                *(f16x4*)&hw[(size_t)grow * H + ct * 16 + lq * 4] = o;
            }
        }
    }
}

// ---------------------------------------------------------------- aggregation (fp16 out)
// out[d] = relu(dis[d] * sum_slots hw'[slot] + bias); slots = [self]+edges+pads, pad-to-8
// nit8 is wave-uniform: special-case 1/2/3 with ALL gathers issued flat (2/4/6 in flight),
// vectorized int2/int4 edata loads; generic loop only for nit8>=4 (12% of waves).
__global__ __launch_bounds__(256) void agg_kernel(const f16* __restrict__ hw,
                                                  const float* __restrict__ dis,
                                                  const int* __restrict__ offs_pk,
                                                  const int* __restrict__ edata,
                                                  const float* __restrict__ bias,
                                                  f16* __restrict__ outh) {
    int wid  = threadIdx.x >> 6;
    int lane = threadIdx.x & 63;
    int node = blockIdx.x * 4 + wid;
    if (node >= NN) return;
    int q  = lane >> 4;
    int j8 = (lane & 15) * 8;
    int w = offs_pk[node];
    int beg = w & 0x3FFFFF;
    int nit8 = (unsigned)w >> 22;
    float acc[8];
    #pragma unroll
    for (int u = 0; u < 8; ++u) acc[u] = 0.f;

    if (nit8 == 2) {
        int4 s = *(const int4*)&edata[beg + q * 4];
        f16x8 v0 = *(const f16x8*)&hw[(size_t)s.x * H + j8];
        f16x8 v1 = *(const f16x8*)&hw[(size_t)s.y * H + j8];
        f16x8 v2 = *(const f16x8*)&hw[(size_t)s.z * H + j8];
        f16x8 v3 = *(const f16x8*)&hw[(size_t)s.w * H + j8];
        f16x8 vt = (v0 + v1) + (v2 + v3);
        #pragma unroll
        for (int u = 0; u < 8; ++u) acc[u] += (float)vt[u];
    } else if (nit8 == 3) {
        int4 s  = *(const int4*)&edata[beg + q * 4];
        int2 s2 = *(const int2*)&edata[beg + 16 + q * 2];
        f16x8 v0 = *(const f16x8*)&hw[(size_t)s.x * H + j8];
        f16x8 v1 = *(const f16x8*)&hw[(size_t)s.y * H + j8];
        f16x8 v2 = *(const f16x8*)&hw[(size_t)s.z * H + j8];
        f16x8 v3 = *(const f16x8*)&hw[(size_t)s.w * H + j8];
        f16x8 v4 = *(const f16x8*)&hw[(size_t)s2.x * H + j8];
        f16x8 v5 = *(const f16x8*)&hw[(size_t)s2.y * H + j8];
        f16x8 vt = ((v0 + v1) + (v2 + v3)) + (v4 + v5);
        #pragma unroll
        for (int u = 0; u < 8; ++u) acc[u] += (float)vt[u];
    } else if (nit8 == 1) {
        int2 s2 = *(const int2*)&edata[beg + q * 2];
        f16x8 v0 = *(const f16x8*)&hw[(size_t)s2.x * H + j8];
        f16x8 v1 = *(const f16x8*)&hw[(size_t)s2.y * H + j8];
        f16x8 vt = v0 + v1;
        #pragma unroll
        for (int u = 0; u < 8; ++u) acc[u] += (float)vt[u];
    } else {
        int it = 0;
        for (; it + 2 <= nit8; it += 2) {
            int4 s = *(const int4*)&edata[beg + it * 8 + q * 4];
            f16x8 v0 = *(const f16x8*)&hw[(size_t)s.x * H + j8];
            f16x8 v1 = *(const f16x8*)&hw[(size_t)s.y * H + j8];
            f16x8 v2 = *(const f16x8*)&hw[(size_t)s.z * H + j8];
            f16x8 v3 = *(const f16x8*)&hw[(size_t)s.w * H + j8];
            f16x8 vt = (v0 + v1) + (v2 + v3);
            #pragma unroll
            for (int u = 0; u < 8; ++u) acc[u] += (float)vt[u];
        }
        if (nit8 & 1) {
            int2 s2 = *(const int2*)&edata[beg + (nit8 - 1) * 8 + q * 2];
            f16x8 v0 = *(const f16x8*)&hw[(size_t)s2.x * H + j8];
            f16x8 v1 = *(const f16x8*)&hw[(size_t)s2.y * H + j8];
            f16x8 vt = v0 + v1;
            #pragma unroll
            for (int u = 0; u < 8; ++u) acc[u] += (float)vt[u];
        }
    }
    #pragma unroll
    for (int u = 0; u < 8; ++u) {
        acc[u] += __shfl_xor(acc[u], 16, 64);
        acc[u] += __shfl_xor(acc[u], 32, 64);
    }
    if (q == 0) {
        float dv = dis[node];
        f16x8 o;
        #pragma unroll
        for (int u = 0; u < 8; ++u) o[u] = (f16)fmaxf(dv * acc[u] + bias[j8 + u], 0.f);
        *(f16x8*)&outh[(size_t)node * H + j8] = o;
    }
}

// ---------------------------------------------------------------- mean-pool + linear head (4-way node-parallel)
__global__ __launch_bounds__(512) void pool_kernel(const f16* __restrict__ h,
                                                   const int* __restrict__ batch,
                                                   const float* __restrict__ linW,
                                                   const float* __restrict__ linb,
                                                   float* __restrict__ out) {
    __shared__ float pld[4][H];
    int g = blockIdx.x;
    int t = threadIdx.x;
    int f = t & 127, quad = t >> 7;
    int lo = lower_bound_i(batch, NN, g);
    int hi = lower_bound_i(batch, NN, g + 1);
    float sum = 0.f;
    for (int n = lo + quad; n < hi; n += 4) sum += (float)h[(size_t)n * H + f];
    pld[quad][f] = sum;
    __syncthreads();
    if (t < H) {
        float cnt = (float)(hi - lo);
        pld[0][t] = (pld[0][t] + pld[1][t] + pld[2][t] + pld[3][t]) / fmaxf(cnt, 1.0f);
    }
    __syncthreads();
    if (t < NC) {
        float acc = linb[t];
        #pragma unroll 4
        for (int j = 0; j < H; ++j) acc += pld[0][j] * linW[j * NC + t];
        out[g * NC + t] = acc;
    }
}

// ---------------------------------------------------------------- launch
extern "C" void kernel_launch(void* const* d_in, const int* in_sizes, int n_in,
                              void* d_out, int out_size, void* d_ws, size_t ws_size,
                              hipStream_t stream) {
    const float* x     = (const float*)d_in[0];
    const int*   ei    = (const int*)d_in[1];
    const int*   batch = (const int*)d_in[2];
    const float* W0    = (const float*)d_in[3];
    const float* b0    = (const float*)d_in[4];
    const float* Ws    = (const float*)d_in[5];
    const float* bs    = (const float*)d_in[6];
    const float* linW  = (const float*)d_in[7];
    const float* linb  = (const float*)d_in[8];
    const int* src = ei;
    const int* dst = ei + NE;

    char* p = (char*)d_ws;
    auto alloc = [&](size_t bytes) -> void* {
        void* r = (void*)p;
        p += (bytes + 255) & ~(size_t)255;
        return r;
    };
    f16*   buf0    = (f16*)alloc((size_t)NN * H * 2);
    f16*   buf1    = (f16*)alloc((size_t)NN * H * 2);
    f16*   buf2    = (f16*)alloc((size_t)NN * H * 2);
    f16*   hwb     = (f16*)alloc((size_t)(NN + 1) * H * 2);   // row NN = zero row for pads
    float* dis     = (float*)alloc((size_t)NN * 4);
    int*   offs_pk = (int*)alloc((size_t)NN * 4);
    int*   binned  = (int*)alloc((size_t)NBUCK * BINCAP * 4);
    int*   edata   = (int*)alloc((size_t)NBUCK * EDCAP * 4);
    int*   bcur    = (int*)alloc((size_t)NBUCK * 4);

    hipMemsetAsync(bcur, 0, (size_t)NBUCK * 4, stream);

    binA_kernel<<<(NE + CHUNK - 1) / CHUNK, 512, 0, stream>>>(src, dst, bcur, binned);
    binB_kernel<<<NBUCK, 256, 0, stream>>>(binned, bcur, edata, offs_pk, dis, hwb);

    int gemm_grid = (NN + 255) / 256;
    int agg_grid  = (NN + 3) / 4;
    size_t HH = (size_t)H * H;

    gemm_kernel<1><<<gemm_grid, 512, 0, stream>>>(x, nullptr, W0, dis, hwb);
    agg_kernel<<<agg_grid, 256, 0, stream>>>(hwb, dis, offs_pk, edata, b0, buf0);
    gemm_kernel<0><<<gemm_grid, 512, 0, stream>>>(buf0, nullptr, Ws, dis, hwb);
    agg_kernel<<<agg_grid, 256, 0, stream>>>(hwb, dis, offs_pk, edata, bs, buf1);
    gemm_kernel<0><<<gemm_grid, 512, 0, stream>>>(buf1, buf0, Ws + HH, dis, hwb);
    agg_kernel<<<agg_grid, 256, 0, stream>>>(hwb, dis, offs_pk, edata, bs + H, buf2);
    gemm_kernel<0><<<gemm_grid, 512, 0, stream>>>(buf2, buf1, Ws + 2 * HH, dis, hwb);
    agg_kernel<<<agg_grid, 256, 0, stream>>>(hwb, dis, offs_pk, edata, bs + 2 * H, buf0);

    pool_kernel<<<NG, 512, 0, stream>>>(buf0, batch, linW, linb, (float*)d_out);
}